// Round 8
// baseline (318.673 us; speedup 1.0000x reference)
//
#include <hip/hip_runtime.h>
#include <math.h>

typedef __bf16 bf16x8 __attribute__((ext_vector_type(8)));
typedef float f32x4 __attribute__((ext_vector_type(4)));

__device__ __forceinline__ bf16x8 to_bf16x8(float4 a, float4 b) {
    bf16x8 r;
    r[0] = (__bf16)a.x; r[1] = (__bf16)a.y; r[2] = (__bf16)a.z; r[3] = (__bf16)a.w;
    r[4] = (__bf16)b.x; r[5] = (__bf16)b.y; r[6] = (__bf16)b.z; r[7] = (__bf16)b.w;
    return r;
}
#define MFMA16(A, B, C) __builtin_amdgcn_mfma_f32_16x16x32_bf16((A), (B), (C), 0, 0, 0)

__device__ __forceinline__ float rsum32(float v) {
    v += __shfl_xor(v, 1, 32); v += __shfl_xor(v, 2, 32);
    v += __shfl_xor(v, 4, 32); v += __shfl_xor(v, 8, 32);
    v += __shfl_xor(v, 16, 32);
    return v;
}
__device__ __forceinline__ float rmax32(float v) {
    v = fmaxf(v, __shfl_xor(v, 1, 32)); v = fmaxf(v, __shfl_xor(v, 2, 32));
    v = fmaxf(v, __shfl_xor(v, 4, 32)); v = fmaxf(v, __shfl_xor(v, 8, 32));
    v = fmaxf(v, __shfl_xor(v, 16, 32));
    return v;
}

// matvec via 32 static broadcast shuffles (no LDS round-trip on the chain):
// OUT[k] = sum_j EV[j] * (t broadcast from lane j of the 32-lane half)
#define SHFL_MATVEC(T, EV, OUT)                                                \
    {                                                                          \
        float a0_ = 0.f, a1_ = 0.f, a2_ = 0.f, a3_ = 0.f;                      \
        _Pragma("unroll") for (int j_ = 0; j_ < 32; j_ += 4) {                 \
            a0_ += EV[j_ + 0] * __shfl((T), j_ + 0, 32);                       \
            a1_ += EV[j_ + 1] * __shfl((T), j_ + 1, 32);                       \
            a2_ += EV[j_ + 2] * __shfl((T), j_ + 2, 32);                       \
            a3_ += EV[j_ + 3] * __shfl((T), j_ + 3, 32);                       \
        }                                                                      \
        OUT = (a0_ + a1_) + (a2_ + a3_);                                       \
    }

// ---------------------------------------------------------------------------
// k_word: fused per-word pipeline, 128 threads (2 waves), 1 word/block.
// A: MFMA dots -> LDS.  B: gd = exp(dots - rowmax).
// C: alpha (wave0) || beta (wave1), unnormalized with register renorm every
//    8 steps (exact; beta boundary factors in bscale[], validated r7).
//    Matvec via broadcast shuffles; Unb/Mb stores are background-only.
// D: p1 -> Pdiff; rank-1 S -> LDS Sb; dT row = -E.*S (+hist atomics), private.
// ---------------------------------------------------------------------------
__global__ __launch_bounds__(128) void k_word(const float* __restrict__ data,
                                              const float* __restrict__ W,
                                              const float* __restrict__ Tm,
                                              const int* __restrict__ labels,
                                              float* __restrict__ Pdiff,
                                              float* __restrict__ dTpart) {
    __shared__ __align__(16) float gdb[2048];  // raw dots -> gd
    __shared__ __align__(16) float Unb[2048];  // alpha*gd (per-i arbitrary scale)
    __shared__ __align__(16) float Mb[2048];   // beta chain values
    __shared__ float Sb[1024];
    __shared__ float bscale[64];
    __shared__ int lab[64];

    const int n = blockIdx.x;
    const int tid = threadIdx.x;
    const int wv = tid >> 6;       // 0: alpha, 1: beta
    const int lane = tid & 63;
    const int k = tid & 31;
    const int hw = tid >> 5;       // half-wave id 0..3
    float* drow = Pdiff + (size_t)n * 2048;

    // ---- Phase A: MFMA dots into LDS ----
    {
        const int m16 = lane & 15;
        const int kb = lane >> 4;
        const size_t row0 = (size_t)n * 64 + wv * 32;
        const float* arow0 = data + (row0 + m16) * 512 + kb * 8;
        const float* arow1 = arow0 + 16 * 512;
        const float* brow0 = W + (size_t)m16 * 512 + kb * 8;
        const float* brow1 = brow0 + 16 * 512;

        f32x4 acc00 = {0.f, 0.f, 0.f, 0.f}, acc01 = {0.f, 0.f, 0.f, 0.f};
        f32x4 acc10 = {0.f, 0.f, 0.f, 0.f}, acc11 = {0.f, 0.f, 0.f, 0.f};

#pragma unroll 1   // full unroll spills (r3: 256 VGPR, 400 MB scratch)
        for (int kk = 0; kk < 16; ++kk) {
            const int off = kk * 32;
            float4 a0l = *(const float4*)(arow0 + off);
            float4 a0h = *(const float4*)(arow0 + off + 4);
            float4 a1l = *(const float4*)(arow1 + off);
            float4 a1h = *(const float4*)(arow1 + off + 4);
            float4 b0l = *(const float4*)(brow0 + off);
            float4 b0h = *(const float4*)(brow0 + off + 4);
            float4 b1l = *(const float4*)(brow1 + off);
            float4 b1h = *(const float4*)(brow1 + off + 4);
            bf16x8 a0 = to_bf16x8(a0l, a0h), a1 = to_bf16x8(a1l, a1h);
            bf16x8 b0 = to_bf16x8(b0l, b0h), b1 = to_bf16x8(b1l, b1h);
            acc00 = MFMA16(a0, b0, acc00);
            acc01 = MFMA16(a0, b1, acc01);
            acc10 = MFMA16(a1, b0, acc10);
            acc11 = MFMA16(a1, b1, acc11);
        }
        const int ib = wv * 32 + kb * 4;
#pragma unroll
        for (int r = 0; r < 4; ++r) {
            gdb[(ib + r) * 32 + m16]           = acc00[r];
            gdb[(ib + r) * 32 + 16 + m16]      = acc01[r];
            gdb[(ib + 16 + r) * 32 + m16]      = acc10[r];
            gdb[(ib + 16 + r) * 32 + 16 + m16] = acc11[r];
        }
    }
#pragma unroll
    for (int i = 0; i < 8; ++i) Sb[tid * 8 + i] = 0.f;
    if (tid < 64) { lab[tid] = labels[n * 64 + tid]; bscale[tid] = 1.f; }
    __syncthreads();

    // ---- Phase B: gd[i][k] = exp(dots - rowmax) ----
#pragma unroll
    for (int ii = 0; ii < 16; ++ii) {
        int i = hw * 16 + ii;
        float d = gdb[i * 32 + k];
        float mx = rmax32(d);
        gdb[i * 32 + k] = __expf(d - mx);
    }
    __syncthreads();

    // ---- Phase C: alpha || beta (deferred norm, shuffle matvec) ----
    if (wv == 0) {
        float Ecol[32];
#pragma unroll
        for (int j = 0; j < 32; ++j) Ecol[j] = __expf(Tm[j * 32 + k]);
        float Areg = 1.f;
        float gdc = gdb[k];
#pragma unroll 1
        for (int g = 0; g < 8; ++g) {
#pragma unroll
            for (int ii = 0; ii < 8; ++ii) {
                const int i = g * 8 + ii;
                float t = Areg * gdc;
                Unb[i * 32 + k] = t;        // background store (read in phase D)
                if (i < 63) {
                    gdc = gdb[(i + 1) * 32 + k];
                    float anew;
                    SHFL_MATVEC(t, Ecol, anew);
                    Areg = anew;
                }
            }
            if (g < 7) Areg *= __builtin_amdgcn_rcpf(rsum32(Areg));
        }
    } else {
        float Erow[32];
#pragma unroll
        for (int j = 0; j < 32; ++j) Erow[j] = __expf(Tm[k * 32 + j]);
        float Mreg = 1.f;
        Mb[63 * 32 + k] = 1.f;
        float gdc = gdb[63 * 32 + k];
#pragma unroll 1
        for (int g = 0; g < 8; ++g) {
#pragma unroll
            for (int ii = 0; ii < 8; ++ii) {
                const int s = g * 8 + ii;
                if (s < 63) {
                    const int i = 63 - s;
                    float ww = gdc * Mreg;
                    gdc = gdb[(i - 1) * 32 + k];
                    float m2;
                    SHFL_MATVEC(ww, Erow, m2);
                    Mb[(i - 1) * 32 + k] = m2;   // background store
                    Mreg = m2;
                }
            }
            if (g < 7) {
                float rc = __builtin_amdgcn_rcpf(rsum32(Mreg));
                Mreg *= rc;
                // next write is Mb[54-8g] carrying extra factor rc
                if (lane == 0) bscale[54 - 8 * g] = rc;
            }
        }
    }
    __syncthreads();

    // ---- Phase D: p-phase, 4 half-waves x 16 positions ----
    float Scol[32];
#pragma unroll
    for (int j = 0; j < 32; ++j) Scol[j] = 0.f;
    const int i0 = hw * 16;
    for (int ii = 0; ii < 16; ++ii) {
        const int i = i0 + ii;
        float un = Unb[i * 32 + k];
        float mm = Mb[i * 32 + k];
        float t = un * mm;
        float Z = rsum32(t);
        float rZ = __builtin_amdgcn_rcpf(Z);
        float pd = ((lab[i] == k) ? 1.f : 0.f) - t * rZ;
        drow[i * 32 + k] = pd;
        if (i < 63) {
            float f = gdb[(i + 1) * 32 + k] * Mb[(i + 1) * 32 + k] * rZ * bscale[i];
            const float4* uv = (const float4*)(&Unb[i * 32]);
#pragma unroll
            for (int j8 = 0; j8 < 8; ++j8) {
                float4 u = uv[j8];
                Scol[j8 * 4 + 0] += u.x * f; Scol[j8 * 4 + 1] += u.y * f;
                Scol[j8 * 4 + 2] += u.z * f; Scol[j8 * 4 + 3] += u.w * f;
            }
        }
    }
#pragma unroll
    for (int j = 0; j < 32; ++j) atomicAdd(&Sb[j * 32 + k], Scol[j]);
    __syncthreads();

    float* op = dTpart + (size_t)n * 1024;
#pragma unroll
    for (int e = 0; e < 8; ++e) {
        int idx = tid * 8 + e;
        op[idx] = -__expf(Tm[idx]) * Sb[idx];
    }
    __syncthreads();
    // pair-label histogram into the block's PRIVATE dT row (no contention)
    if (tid < 63) atomicAdd(&op[lab[tid] * 32 + lab[tid + 1]], 1.0f);
}

// ---------------------------------------------------------------------------
// K3: dw partials = Pdiff^T @ data. grid = 256 word-groups x 4 d-quarters.
// ---------------------------------------------------------------------------
__global__ __launch_bounds__(256) void k_dw(const float* __restrict__ data,
                                            const float* __restrict__ Pd,
                                            float* __restrict__ dwp) {
    const int g = blockIdx.x >> 2;
    const int q = blockIdx.x & 3;
    const int tid = threadIdx.x;
    const int kg = __builtin_amdgcn_readfirstlane(tid >> 6);
    const int lane = tid & 63;
    const int k0 = kg << 3;
    const int d0 = q * 128 + lane * 2;

    float2 acc[8];
#pragma unroll
    for (int i = 0; i < 8; ++i) acc[i] = make_float2(0.f, 0.f);

    const size_t rbase = (size_t)g * 512;
    const float* dptr = data + rbase * 512 + d0;
    const float4* pptr = (const float4*)(Pd + rbase * 32) + kg * 2;

#define FMA8_2(PA, PB, DV)                                                     \
    acc[0].x += (PA).x * (DV).x; acc[0].y += (PA).x * (DV).y;                  \
    acc[1].x += (PA).y * (DV).x; acc[1].y += (PA).y * (DV).y;                  \
    acc[2].x += (PA).z * (DV).x; acc[2].y += (PA).z * (DV).y;                  \
    acc[3].x += (PA).w * (DV).x; acc[3].y += (PA).w * (DV).y;                  \
    acc[4].x += (PB).x * (DV).x; acc[4].y += (PB).x * (DV).y;                  \
    acc[5].x += (PB).y * (DV).x; acc[5].y += (PB).y * (DV).y;                  \
    acc[6].x += (PB).z * (DV).x; acc[6].y += (PB).z * (DV).y;                  \
    acc[7].x += (PB).w * (DV).x; acc[7].y += (PB).w * (DV).y;

    for (int r = 0; r < 512; r += 4) {
        float2 dv0 = *(const float2*)(dptr + (size_t)(r + 0) * 512);
        float2 dv1 = *(const float2*)(dptr + (size_t)(r + 1) * 512);
        float2 dv2 = *(const float2*)(dptr + (size_t)(r + 2) * 512);
        float2 dv3 = *(const float2*)(dptr + (size_t)(r + 3) * 512);
        float4 pa0 = pptr[(r + 0) * 8], pb0 = pptr[(r + 0) * 8 + 1];
        float4 pa1 = pptr[(r + 1) * 8], pb1 = pptr[(r + 1) * 8 + 1];
        float4 pa2 = pptr[(r + 2) * 8], pb2 = pptr[(r + 2) * 8 + 1];
        float4 pa3 = pptr[(r + 3) * 8], pb3 = pptr[(r + 3) * 8 + 1];
        FMA8_2(pa0, pb0, dv0)
        FMA8_2(pa1, pb1, dv1)
        FMA8_2(pa2, pb2, dv2)
        FMA8_2(pa3, pb3, dv3)
    }
#undef FMA8_2

    float* op = dwp + (size_t)g * 16384;
#pragma unroll
    for (int kk = 0; kk < 8; ++kk)
        *(float2*)(op + (k0 + kk) * 512 + d0) = acc[kk];
}

// ---------------------------------------------------------------------------
// K4: reduce partials, scale 1/N. blocks 0..255: dw (64 outs each);
// blocks 256..319: dT (16 outs each).
// ---------------------------------------------------------------------------
__global__ __launch_bounds__(256) void k_final(const float* __restrict__ dwp,
                                               const float* __restrict__ dTp,
                                               float* __restrict__ out) {
    __shared__ float red[256];
    const int b = blockIdx.x, t = threadIdx.x;
    const float inv = 1.0f / 2048.0f;
    if (b < 256) {
        const int q = t >> 6, ol = t & 63;
        const int oi = b * 64 + ol;
        float s = 0.f;
#pragma unroll 4
        for (int j = 0; j < 64; ++j) s += dwp[(size_t)(q * 64 + j) * 16384 + oi];
        red[t] = s;
        __syncthreads();
        if (t < 64) out[b * 64 + t] = (red[t] + red[t + 64] + red[t + 128] + red[t + 192]) * inv;
    } else {
        const int ol = t >> 4, q = t & 15;
        const int oi = (b - 256) * 16 + ol;
        float s = 0.f;
#pragma unroll 4
        for (int j = 0; j < 128; ++j) s += dTp[(size_t)(q * 128 + j) * 1024 + oi];
        s += __shfl_xor(s, 1, 16); s += __shfl_xor(s, 2, 16);
        s += __shfl_xor(s, 4, 16); s += __shfl_xor(s, 8, 16);
        if (q == 0) out[16384 + oi] = s * inv;
    }
}

// ---------------------------------------------------------------------------
// ws layout (floats): [0,4194304) Pdiff | [4194304,6291456) dT partials
//                     [6291456,10485760) dw partials
// ---------------------------------------------------------------------------
extern "C" void kernel_launch(void* const* d_in, const int* in_sizes, int n_in,
                              void* d_out, int out_size, void* d_ws, size_t ws_size,
                              hipStream_t stream) {
    const float* W = (const float*)d_in[0];
    const float* Tm = (const float*)d_in[1];
    const float* data = (const float*)d_in[2];
    const int* labels = (const int*)d_in[3];
    float* out = (float*)d_out;
    float* ws = (float*)d_ws;

    float* Pdiff = ws;                 // 2048*64*32
    float* dTpart = ws + 4194304;      // 2048*1024
    float* dwpart = ws + 6291456;      // 256*16384

    hipLaunchKernelGGL(k_word, dim3(2048), dim3(128), 0, stream,
                       data, W, Tm, labels, Pdiff, dTpart);
    hipLaunchKernelGGL(k_dw, dim3(1024), dim3(256), 0, stream, data, Pdiff, dwpart);
    hipLaunchKernelGGL(k_final, dim3(320), dim3(256), 0, stream, dwpart, dTpart, out);
}

// Round 10
// 275.743 us; speedup vs baseline: 1.1557x; 1.1557x over previous
//
#include <hip/hip_runtime.h>
#include <math.h>

typedef __bf16 bf16x8 __attribute__((ext_vector_type(8)));
typedef float f32x4 __attribute__((ext_vector_type(4)));

__device__ __forceinline__ bf16x8 to_bf16x8(float4 a, float4 b) {
    bf16x8 r;
    r[0] = (__bf16)a.x; r[1] = (__bf16)a.y; r[2] = (__bf16)a.z; r[3] = (__bf16)a.w;
    r[4] = (__bf16)b.x; r[5] = (__bf16)b.y; r[6] = (__bf16)b.z; r[7] = (__bf16)b.w;
    return r;
}
#define MFMA16(A, B, C) __builtin_amdgcn_mfma_f32_16x16x32_bf16((A), (B), (C), 0, 0, 0)

__device__ __forceinline__ float rsum32(float v) {
    v += __shfl_xor(v, 1, 32); v += __shfl_xor(v, 2, 32);
    v += __shfl_xor(v, 4, 32); v += __shfl_xor(v, 8, 32);
    v += __shfl_xor(v, 16, 32);
    return v;
}
__device__ __forceinline__ float rmax32(float v) {
    v = fmaxf(v, __shfl_xor(v, 1, 32)); v = fmaxf(v, __shfl_xor(v, 2, 32));
    v = fmaxf(v, __shfl_xor(v, 4, 32)); v = fmaxf(v, __shfl_xor(v, 8, 32));
    v = fmaxf(v, __shfl_xor(v, 16, 32));
    return v;
}

// broadcast lane j (0..31) of a value that is DUPLICATED across both 32-lane
// halves of the wave (phase-C chain state only!). VALU readlane -> SGPR, no
// DS-pipe traffic. NOT valid for per-half-wave data (r9 bug: phase D).
__device__ __forceinline__ float rl(float v, int j) {
    return __int_as_float(__builtin_amdgcn_readlane(__float_as_int(v), j));
}

// matvec OUT[k] = sum_j EV[j] * t[j] via 32 readlane broadcasts (VALU-only).
#define RL_MATVEC(T, EV, OUT)                                                  \
    {                                                                          \
        float a0_ = 0.f, a1_ = 0.f, a2_ = 0.f, a3_ = 0.f;                      \
        _Pragma("unroll") for (int j_ = 0; j_ < 32; j_ += 4) {                 \
            a0_ += EV[j_ + 0] * rl((T), j_ + 0);                               \
            a1_ += EV[j_ + 1] * rl((T), j_ + 1);                               \
            a2_ += EV[j_ + 2] * rl((T), j_ + 2);                               \
            a3_ += EV[j_ + 3] * rl((T), j_ + 3);                               \
        }                                                                      \
        OUT = (a0_ + a1_) + (a2_ + a3_);                                       \
    }

// ---------------------------------------------------------------------------
// k_word: fused per-word pipeline, 128 threads (2 waves), 1 word/block.
// A: MFMA dots -> LDS (unroll 2).  B: gd = exp(dots - rowmax).
// C: alpha (wave0) || beta (wave1), deferred norm (renorm every 8 steps,
//    exact; beta boundary factors in bscale[]), readlane matvec (chain state
//    is duplicated across wave halves -> readlane is valid HERE).
// D: p1 -> Pdiff; rank-1 S via LDS same-address float4 broadcasts (per-half
//    -wave data, readlane NOT valid -> r9 bug); -E.*S + hist atomics into the
//    block's PRIVATE dTpart row (pre-zeroed by memset).
// LDS 24.5 KB -> 6 blocks/CU.
// ---------------------------------------------------------------------------
__global__ __launch_bounds__(128) void k_word(const float* __restrict__ data,
                                              const float* __restrict__ W,
                                              const float* __restrict__ Tm,
                                              const int* __restrict__ labels,
                                              float* __restrict__ Pdiff,
                                              float* __restrict__ dTpart) {
    __shared__ __align__(16) float gdb[2048];  // raw dots -> gd
    __shared__ __align__(16) float Unb[2048];  // alpha*gd (per-i arbitrary scale)
    __shared__ __align__(16) float Mb[2048];   // beta chain values
    __shared__ float bscale[64];
    __shared__ int lab[64];

    const int n = blockIdx.x;
    const int tid = threadIdx.x;
    const int wv = tid >> 6;       // 0: alpha, 1: beta
    const int lane = tid & 63;
    const int k = tid & 31;
    const int hw = tid >> 5;       // half-wave id 0..3
    float* drow = Pdiff + (size_t)n * 2048;

    // ---- Phase A: MFMA dots into LDS ----
    {
        const int m16 = lane & 15;
        const int kb = lane >> 4;
        const size_t row0 = (size_t)n * 64 + wv * 32;
        const float* arow0 = data + (row0 + m16) * 512 + kb * 8;
        const float* arow1 = arow0 + 16 * 512;
        const float* brow0 = W + (size_t)m16 * 512 + kb * 8;
        const float* brow1 = brow0 + 16 * 512;

        f32x4 acc00 = {0.f, 0.f, 0.f, 0.f}, acc01 = {0.f, 0.f, 0.f, 0.f};
        f32x4 acc10 = {0.f, 0.f, 0.f, 0.f}, acc11 = {0.f, 0.f, 0.f, 0.f};

#pragma unroll 2   // 2-deep: 16 loads in flight; full unroll spills (r3)
        for (int kk = 0; kk < 16; ++kk) {
            const int off = kk * 32;
            float4 a0l = *(const float4*)(arow0 + off);
            float4 a0h = *(const float4*)(arow0 + off + 4);
            float4 a1l = *(const float4*)(arow1 + off);
            float4 a1h = *(const float4*)(arow1 + off + 4);
            float4 b0l = *(const float4*)(brow0 + off);
            float4 b0h = *(const float4*)(brow0 + off + 4);
            float4 b1l = *(const float4*)(brow1 + off);
            float4 b1h = *(const float4*)(brow1 + off + 4);
            bf16x8 a0 = to_bf16x8(a0l, a0h), a1 = to_bf16x8(a1l, a1h);
            bf16x8 b0 = to_bf16x8(b0l, b0h), b1 = to_bf16x8(b1l, b1h);
            acc00 = MFMA16(a0, b0, acc00);
            acc01 = MFMA16(a0, b1, acc01);
            acc10 = MFMA16(a1, b0, acc10);
            acc11 = MFMA16(a1, b1, acc11);
        }
        const int ib = wv * 32 + kb * 4;
#pragma unroll
        for (int r = 0; r < 4; ++r) {
            gdb[(ib + r) * 32 + m16]           = acc00[r];
            gdb[(ib + r) * 32 + 16 + m16]      = acc01[r];
            gdb[(ib + 16 + r) * 32 + m16]      = acc10[r];
            gdb[(ib + 16 + r) * 32 + 16 + m16] = acc11[r];
        }
    }
    if (tid < 64) { lab[tid] = labels[n * 64 + tid]; bscale[tid] = 1.f; }
    __syncthreads();

    // ---- Phase B: gd[i][k] = exp(dots - rowmax) ----
#pragma unroll
    for (int ii = 0; ii < 16; ++ii) {
        int i = hw * 16 + ii;
        float d = gdb[i * 32 + k];
        float mx = rmax32(d);
        gdb[i * 32 + k] = __expf(d - mx);
    }
    __syncthreads();

    // ---- Phase C: alpha || beta (deferred norm, readlane matvec) ----
    if (wv == 0) {
        float Ecol[32];
#pragma unroll
        for (int j = 0; j < 32; ++j) Ecol[j] = __expf(Tm[j * 32 + k]);
        float Areg = 1.f;
        float gdc = gdb[k];
#pragma unroll 1
        for (int g = 0; g < 8; ++g) {
#pragma unroll
            for (int ii = 0; ii < 8; ++ii) {
                const int i = g * 8 + ii;
                float t = Areg * gdc;
                Unb[i * 32 + k] = t;        // background store (read in phase D)
                if (i < 63) {
                    gdc = gdb[(i + 1) * 32 + k];
                    float anew;
                    RL_MATVEC(t, Ecol, anew);
                    Areg = anew;
                }
            }
            if (g < 7) Areg *= __builtin_amdgcn_rcpf(rsum32(Areg));
        }
    } else {
        float Erow[32];
#pragma unroll
        for (int j = 0; j < 32; ++j) Erow[j] = __expf(Tm[k * 32 + j]);
        float Mreg = 1.f;
        Mb[63 * 32 + k] = 1.f;
        float gdc = gdb[63 * 32 + k];
#pragma unroll 1
        for (int g = 0; g < 8; ++g) {
#pragma unroll
            for (int ii = 0; ii < 8; ++ii) {
                const int s = g * 8 + ii;
                if (s < 63) {
                    const int i = 63 - s;
                    float ww = gdc * Mreg;
                    gdc = gdb[(i - 1) * 32 + k];
                    float m2;
                    RL_MATVEC(ww, Erow, m2);
                    Mb[(i - 1) * 32 + k] = m2;   // background store
                    Mreg = m2;
                }
            }
            if (g < 7) {
                float rc = __builtin_amdgcn_rcpf(rsum32(Mreg));
                Mreg *= rc;
                // next write is Mb[54-8g] carrying extra factor rc
                if (lane == 0) bscale[54 - 8 * g] = rc;
            }
        }
    }
    __syncthreads();

    // ---- Phase D: p-phase, 4 half-waves x 16 positions ----
    float EcolD[32];
#pragma unroll
    for (int j = 0; j < 32; ++j) EcolD[j] = __expf(Tm[j * 32 + k]);
    float Scol[32];
#pragma unroll
    for (int j = 0; j < 32; ++j) Scol[j] = 0.f;
    const int i0 = hw * 16;
    for (int ii = 0; ii < 16; ++ii) {
        const int i = i0 + ii;
        float un = Unb[i * 32 + k];
        float mm = Mb[i * 32 + k];
        float t = un * mm;
        float Z = rsum32(t);
        float rZ = __builtin_amdgcn_rcpf(Z);
        float pd = ((lab[i] == k) ? 1.f : 0.f) - t * rZ;
        drow[i * 32 + k] = pd;
        if (i < 63) {
            float f = gdb[(i + 1) * 32 + k] * Mb[(i + 1) * 32 + k] * rZ * bscale[i];
            // per-half-wave data: broadcast via same-address LDS reads
            // (readlane is WRONG here — reads the other half's position; r9 bug)
            const float4* uv = (const float4*)(&Unb[i * 32]);
#pragma unroll
            for (int j8 = 0; j8 < 8; ++j8) {
                float4 u = uv[j8];
                Scol[j8 * 4 + 0] += u.x * f; Scol[j8 * 4 + 1] += u.y * f;
                Scol[j8 * 4 + 2] += u.z * f; Scol[j8 * 4 + 3] += u.w * f;
            }
        }
    }
    // all writes to the block's private dT row are atomic (row pre-zeroed)
    float* op = dTpart + (size_t)n * 1024;
#pragma unroll
    for (int j = 0; j < 32; ++j) atomicAdd(&op[j * 32 + k], -EcolD[j] * Scol[j]);
    if (tid < 63) atomicAdd(&op[lab[tid] * 32 + lab[tid + 1]], 1.0f);
}

// ---------------------------------------------------------------------------
// K3: dw partials = Pdiff^T @ data. grid = 256 word-groups x 4 d-quarters.
// ---------------------------------------------------------------------------
__global__ __launch_bounds__(256) void k_dw(const float* __restrict__ data,
                                            const float* __restrict__ Pd,
                                            float* __restrict__ dwp) {
    const int g = blockIdx.x >> 2;
    const int q = blockIdx.x & 3;
    const int tid = threadIdx.x;
    const int kg = __builtin_amdgcn_readfirstlane(tid >> 6);
    const int lane = tid & 63;
    const int k0 = kg << 3;
    const int d0 = q * 128 + lane * 2;

    float2 acc[8];
#pragma unroll
    for (int i = 0; i < 8; ++i) acc[i] = make_float2(0.f, 0.f);

    const size_t rbase = (size_t)g * 512;
    const float* dptr = data + rbase * 512 + d0;
    const float4* pptr = (const float4*)(Pd + rbase * 32) + kg * 2;

#define FMA8_2(PA, PB, DV)                                                     \
    acc[0].x += (PA).x * (DV).x; acc[0].y += (PA).x * (DV).y;                  \
    acc[1].x += (PA).y * (DV).x; acc[1].y += (PA).y * (DV).y;                  \
    acc[2].x += (PA).z * (DV).x; acc[2].y += (PA).z * (DV).y;                  \
    acc[3].x += (PA).w * (DV).x; acc[3].y += (PA).w * (DV).y;                  \
    acc[4].x += (PB).x * (DV).x; acc[4].y += (PB).x * (DV).y;                  \
    acc[5].x += (PB).y * (DV).x; acc[5].y += (PB).y * (DV).y;                  \
    acc[6].x += (PB).z * (DV).x; acc[6].y += (PB).z * (DV).y;                  \
    acc[7].x += (PB).w * (DV).x; acc[7].y += (PB).w * (DV).y;

    for (int r = 0; r < 512; r += 4) {
        float2 dv0 = *(const float2*)(dptr + (size_t)(r + 0) * 512);
        float2 dv1 = *(const float2*)(dptr + (size_t)(r + 1) * 512);
        float2 dv2 = *(const float2*)(dptr + (size_t)(r + 2) * 512);
        float2 dv3 = *(const float2*)(dptr + (size_t)(r + 3) * 512);
        float4 pa0 = pptr[(r + 0) * 8], pb0 = pptr[(r + 0) * 8 + 1];
        float4 pa1 = pptr[(r + 1) * 8], pb1 = pptr[(r + 1) * 8 + 1];
        float4 pa2 = pptr[(r + 2) * 8], pb2 = pptr[(r + 2) * 8 + 1];
        float4 pa3 = pptr[(r + 3) * 8], pb3 = pptr[(r + 3) * 8 + 1];
        FMA8_2(pa0, pb0, dv0)
        FMA8_2(pa1, pb1, dv1)
        FMA8_2(pa2, pb2, dv2)
        FMA8_2(pa3, pb3, dv3)
    }
#undef FMA8_2

    float* op = dwp + (size_t)g * 16384;
#pragma unroll
    for (int kk = 0; kk < 8; ++kk)
        *(float2*)(op + (k0 + kk) * 512 + d0) = acc[kk];
}

// ---------------------------------------------------------------------------
// K4: reduce partials, scale 1/N. blocks 0..255: dw (64 outs each);
// blocks 256..319: dT (16 outs each).
// ---------------------------------------------------------------------------
__global__ __launch_bounds__(256) void k_final(const float* __restrict__ dwp,
                                               const float* __restrict__ dTp,
                                               float* __restrict__ out) {
    __shared__ float red[256];
    const int b = blockIdx.x, t = threadIdx.x;
    const float inv = 1.0f / 2048.0f;
    if (b < 256) {
        const int q = t >> 6, ol = t & 63;
        const int oi = b * 64 + ol;
        float s = 0.f;
#pragma unroll 4
        for (int j = 0; j < 64; ++j) s += dwp[(size_t)(q * 64 + j) * 16384 + oi];
        red[t] = s;
        __syncthreads();
        if (t < 64) out[b * 64 + t] = (red[t] + red[t + 64] + red[t + 128] + red[t + 192]) * inv;
    } else {
        const int ol = t >> 4, q = t & 15;
        const int oi = (b - 256) * 16 + ol;
        float s = 0.f;
#pragma unroll 4
        for (int j = 0; j < 128; ++j) s += dTp[(size_t)(q * 128 + j) * 1024 + oi];
        s += __shfl_xor(s, 1, 16); s += __shfl_xor(s, 2, 16);
        s += __shfl_xor(s, 4, 16); s += __shfl_xor(s, 8, 16);
        if (q == 0) out[16384 + oi] = s * inv;
    }
}

// ---------------------------------------------------------------------------
// ws layout (floats): [0,4194304) Pdiff | [4194304,6291456) dT partials
//                     [6291456,10485760) dw partials
// ---------------------------------------------------------------------------
extern "C" void kernel_launch(void* const* d_in, const int* in_sizes, int n_in,
                              void* d_out, int out_size, void* d_ws, size_t ws_size,
                              hipStream_t stream) {
    const float* W = (const float*)d_in[0];
    const float* Tm = (const float*)d_in[1];
    const float* data = (const float*)d_in[2];
    const int* labels = (const int*)d_in[3];
    float* out = (float*)d_out;
    float* ws = (float*)d_ws;

    float* Pdiff = ws;                 // 2048*64*32
    float* dTpart = ws + 4194304;      // 2048*1024
    float* dwpart = ws + 6291456;      // 256*16384

    hipMemsetAsync(dTpart, 0, 2048 * 1024 * sizeof(float), stream);
    hipLaunchKernelGGL(k_word, dim3(2048), dim3(128), 0, stream,
                       data, W, Tm, labels, Pdiff, dTpart);
    hipLaunchKernelGGL(k_dw, dim3(1024), dim3(256), 0, stream, data, Pdiff, dwpart);
    hipLaunchKernelGGL(k_final, dim3(320), dim3(256), 0, stream, dwpart, dTpart, out);
}